// Round 1
// baseline (214.214 us; speedup 1.0000x reference)
//
#include <hip/hip_runtime.h>
#include <math.h>

#define NB 2
#define NCH 192
#define NH 48
#define NW 48
#define NL 2304
#define NK 4
#define NN 16
#define NR 12
#define ND 44
#define NCHUNK 144
#define CLEN 16                     // NL / NCHUNK
#define LTILE 16
#define NLT (NL / LTILE)            // 144 (== NCHUNK, tile == chunk)
#define HLEN 8                      // half-chunk length (scan split)

// workspace float sizes
#define SZ_XT    (NB * NCH * NL)                 // 884736
#define SZ_UT0   (NB * NL * NCH)                 // 884736
#define SZ_CB    (NB * NK * NL * NN)             // 294912
#define SZ_CUMS  (NB * NK * NL * NCH)            // 3538944
#define SZ_YBUF  (NB * NK * NL * NCH)            // 3538944
#define SZ_HEND  (NB * NK * NCHUNK * NCH * NN)   // 3538944

// --------------------------------------------- prep: xT + ut0 (one launch)
__global__ __launch_bounds__(256) void k_prep(const float* __restrict__ x,
                                              float* __restrict__ xT,
                                              float* __restrict__ ut0) {
    __shared__ float tile[64 * 193];
    int bid = blockIdx.x;
    if (bid < NB * NCH) {
        // xT[b][c][w*48+h] = x[b][c][h*48+w]
        const float* src = x + (size_t)bid * NL;
        float* dst = xT + (size_t)bid * NL;
        for (int i = threadIdx.x; i < NL; i += 256) {
            int h = i / NW, w = i % NW;
            tile[w * 49 + h] = src[i];
        }
        __syncthreads();
        for (int i = threadIdx.x; i < NL; i += 256) {
            dst[i] = tile[i + i / NH];
        }
    } else {
        // ut0[b][l][c] = x[b][c][l]
        int t = bid - NB * NCH;                // 0..71
        int b = t / 36, lt = t % 36;
        int l0 = lt * 64;
        const float* bx = x + (size_t)b * NCH * NL;
        for (int i = threadIdx.x; i < NCH * 64; i += 256) {
            int c = i >> 6, j = i & 63;        // coalesced read along l
            tile[j * 193 + c] = bx[(size_t)c * NL + l0 + j];
        }
        __syncthreads();
        float* bo = ut0 + (size_t)b * NL * NCH;
        for (int i = threadIdx.x; i < NCH * 64; i += 256) {
            int j = i / NCH, c = i % NCH;      // coalesced write along c
            bo[(size_t)(l0 + j) * NCH + c] = tile[j * 193 + c];
        }
    }
}

__device__ __forceinline__ int u_row(int k, int l) {
    int pos = (k >= 2) ? (NL - 1 - l) : l;
    if (k & 1) pos = (pos % 48) * 48 + (pos / 48);
    return pos;
}

// ---- fused proj + delta + chunk-local scan emitting y_local.
// 384 threads: proj uses 352 lanes (44 dt x 4 lt x 2 cc-halves); the scan
// phase splits the 16-step chunk into lower (waves 0-2, l 0..7) and upper
// (waves 3-5, l 8..15) halves with a mid-state handoff through LDS.
__global__ __launch_bounds__(384) void k_projscan(const float* __restrict__ x,
                                                  const float* __restrict__ xT,
                                                  const float* __restrict__ xpw,
                                                  const float* __restrict__ dtw,
                                                  const float* __restrict__ dt_bias,
                                                  const float* __restrict__ A_logs,
                                                  const float* __restrict__ Ds,
                                                  const float* __restrict__ ut0,
                                                  float* __restrict__ Cbuf,
                                                  float* __restrict__ cumS,
                                                  float* __restrict__ ybuf,
                                                  float* __restrict__ Hend) {
    __shared__ float smem[6560];
    float* WL   = smem;                 // [96][45]  proj weights     (17.3 KB)
    float* XS   = smem + 4320;          // [96][16]  x tile            (6.1 KB)
    float* PACC = smem + 4320;          // alias XS: [4][176] sub-reduce
    float* DTs  = smem + 5856;          // [16][12]
    float* BLs  = smem + 6048;          // [16][16]
    float* CLs  = smem + 6304;          // [16][16]
    float* HMID = smem;                 // alias WL: [16][192] mid h state
    float* SMID = smem + 3072;          // [192]     mid cumS

    int bid = blockIdx.x;               // 8 * 144
    int bk = bid / NLT;
    int chk = bid % NLT;
    int lt0 = chk * LTILE;
    int b = bk >> 2, k = bk & 3;
    int tid = threadIdx.x;
    const float* bx = ((k & 1) ? xT : x) + (size_t)b * NCH * NL;
    bool rev = (k >= 2);

    int dt = tid % ND;                  // 0..43
    int q  = tid / ND;                  // 0..7 for tid<352
    int plt = q & 3;                    // l-group (4 l each)
    float acc[4] = {0.0f, 0.0f, 0.0f, 0.0f};
    for (int ph = 0; ph < 2; ++ph) {
        int c0 = ph * 96;
        __syncthreads();
        for (int i = tid; i < 96 * ND; i += 384) {
            int d = i / 96, cc = i % 96;          // coalesced along cc
            WL[cc * 45 + d] = xpw[((size_t)k * ND + d) * NCH + c0 + cc];
        }
        for (int i = tid; i < 96 * LTILE; i += 384) {
            int cc = i >> 4, j = i & 15;
            int gl = lt0 + j;
            if (rev) gl = NL - 1 - gl;
            XS[i] = bx[(size_t)(c0 + cc) * NL + gl];
        }
        __syncthreads();
        if (tid < 352) {
            int ccb = (q >> 2) * 48;              // cc half within phase
#pragma unroll 8
            for (int c2 = 0; c2 < 48; ++c2) {
                int cc = ccb + c2;
                float4 xv = *(const float4*)&XS[cc * LTILE + plt * 4];
                float wv = WL[cc * 45 + dt];
                acc[0] = fmaf(xv.x, wv, acc[0]);
                acc[1] = fmaf(xv.y, wv, acc[1]);
                acc[2] = fmaf(xv.z, wv, acc[2]);
                acc[3] = fmaf(xv.w, wv, acc[3]);
            }
        }
    }
    __syncthreads();                    // XS / WL dead past here
    if (tid >= 176 && tid < 352) {
        int pp = tid - 176;
#pragma unroll
        for (int li = 0; li < 4; ++li) PACC[li * 176 + pp] = acc[li];
    }
    __syncthreads();
    if (tid < 176) {
#pragma unroll
        for (int li = 0; li < 4; ++li) {
            float v = acc[li] + PACC[li * 176 + tid];
            int l = plt * 4 + li;                 // within tile
            if (dt < NR) {
                DTs[l * NR + dt] = v;
            } else if (dt < NR + NN) {
                BLs[l * NN + (dt - NR)] = v;
            } else {
                CLs[l * NN + (dt - NR - NN)] = v;
                Cbuf[((size_t)bk * NL + lt0 + l) * NN + (dt - NR - NN)] = v;
            }
        }
    }
    __syncthreads();
    // ------- scan: thread c of each half does delta+softplus then local scan
    int half = (tid >= NCH) ? 1 : 0;    // wave-aligned split (192 = 3 waves)
    int c = tid - half * NCH;
    int lb = half * HLEN;               // local l offset within chunk
    float A2[NN];
    {
        const float4* ap = (const float4*)(A_logs + ((size_t)(k * NCH + c)) * NN);
        float4 a0 = ap[0], a1 = ap[1], a2 = ap[2], a3 = ap[3];
        float t[16] = {a0.x, a0.y, a0.z, a0.w, a1.x, a1.y, a1.z, a1.w,
                       a2.x, a2.y, a2.z, a2.w, a3.x, a3.y, a3.z, a3.w};
#pragma unroll
        for (int n = 0; n < NN; ++n) A2[n] = -expf(t[n]) * 1.44269504f;
    }
    const float4* wp = (const float4*)(dtw + ((size_t)k * NCH + c) * NR);
    float4 w0 = wp[0], w1 = wp[1], w2 = wp[2];
    float bias = dt_bias[k * NCH + c];
    float dval = Ds[k * NCH + c];
    const float* up = ut0 + (size_t)b * NL * NCH + c;
    float* csp = cumS + (size_t)bk * NL * NCH + c;
    float* yp  = ybuf + (size_t)bk * NL * NCH + c;
    float sp[HLEN], uvv[HLEN], cs[HLEN];
    float S = 0.0f;
#pragma unroll
    for (int i = 0; i < HLEN; ++i) {
        int l = lb + i;
        float4 a0 = *(const float4*)&DTs[l * NR + 0];
        float4 a1 = *(const float4*)&DTs[l * NR + 4];
        float4 a2 = *(const float4*)&DTs[l * NR + 8];
        float p0 = fmaf(w0.x, a0.x, fmaf(w0.y, a0.y, bias));
        float p1 = fmaf(w0.z, a0.z, w0.w * a0.w);
        float p2 = fmaf(w1.x, a1.x, fmaf(w1.y, a1.y, w1.z * a1.z));
        float p3 = fmaf(w1.w, a1.w, fmaf(w2.x, a2.x, w2.y * a2.y));
        float p4 = fmaf(w2.z, a2.z, w2.w * a2.w);
        float acc2 = (p0 + p1) + (p2 + p3) + p4;
        float s = fmaxf(acc2, 0.0f) + log1pf(expf(-fabsf(acc2)));
        sp[i] = s;
        S += s;
        cs[i] = S;
        if (!half) csp[(size_t)(lt0 + l) * NCH] = S;   // lower: final value
        uvv[i] = up[(size_t)u_row(k, lt0 + l) * NCH];
    }
    float h[NN];
#pragma unroll
    for (int n = 0; n < NN; ++n) h[n] = 0.0f;
    float yv[HLEN];
#pragma unroll
    for (int i = 0; i < HLEN; ++i) {
        int l = lb + i;
        float du = sp[i] * uvv[i];
        const float4* br = (const float4*)&BLs[l * NN];
        float4 b0 = br[0], b1 = br[1], b2 = br[2], b3 = br[3];
        float Bv[16] = {b0.x, b0.y, b0.z, b0.w, b1.x, b1.y, b1.z, b1.w,
                        b2.x, b2.y, b2.z, b2.w, b3.x, b3.y, b3.z, b3.w};
        const float4* cr = (const float4*)&CLs[l * NN];
        float4 c0 = cr[0], c1 = cr[1], c2 = cr[2], c3 = cr[3];
        float Cv[16] = {c0.x, c0.y, c0.z, c0.w, c1.x, c1.y, c1.z, c1.w,
                        c2.x, c2.y, c2.z, c2.w, c3.x, c3.y, c3.z, c3.w};
        float y = 0.0f;
#pragma unroll
        for (int n = 0; n < NN; ++n) {
            float dA = exp2f(sp[i] * A2[n]);
            h[n] = fmaf(dA, h[n], du * Bv[n]);
            y = fmaf(h[n], Cv[n], y);
        }
        yv[i] = fmaf(dval, uvv[i], y);
        if (!half) yp[(size_t)(lt0 + l) * NCH] = yv[i]; // lower: final value
    }
    if (!half) {
        // publish mid state for the upper half
#pragma unroll
        for (int n = 0; n < NN; ++n) HMID[n * NCH + c] = h[n];
        SMID[c] = S;
    }
    __syncthreads();
    if (half) {
        float smid = SMID[c];
        float hm[NN];
#pragma unroll
        for (int n = 0; n < NN; ++n) hm[n] = HMID[n * NCH + c];
#pragma unroll
        for (int i = 0; i < HLEN; ++i) {
            int l = lb + i;
            const float4* cr = (const float4*)&CLs[l * NN];
            float4 c0 = cr[0], c1 = cr[1], c2 = cr[2], c3 = cr[3];
            float Cv[16] = {c0.x, c0.y, c0.z, c0.w, c1.x, c1.y, c1.z, c1.w,
                            c2.x, c2.y, c2.z, c2.w, c3.x, c3.y, c3.z, c3.w};
            float corr = 0.0f;
#pragma unroll
            for (int n = 0; n < NN; ++n)
                corr = fmaf(Cv[n] * hm[n], exp2f(cs[i] * A2[n]), corr);
            yp[(size_t)(lt0 + l) * NCH] = yv[i] + corr;
            csp[(size_t)(lt0 + l) * NCH] = cs[i] + smid;
        }
        // chunk-end state: h_end = exp2(S_hi*A2) ∘ h_mid + h_local_end
        size_t ob = (((size_t)bk * NCHUNK + chk) * NCH + c) * NN;
        float he[NN];
#pragma unroll
        for (int n = 0; n < NN; ++n) he[n] = fmaf(exp2f(S * A2[n]), hm[n], h[n]);
#pragma unroll
        for (int qq = 0; qq < 4; ++qq)
            *(float4*)&Hend[ob + qq * 4] =
                make_float4(he[qq*4], he[qq*4+1], he[qq*4+2], he[qq*4+3]);
    }
}

// ------------- scan pass 2: parallel chunk prefix (Hillis-Steele in LDS).
// One block per (bk,c): thread j owns chunk j's (P,E) pair (16 n in regs).
// After this kernel Hend[j] holds the INCOMING state for chunk j.
#define SP2 17
__global__ __launch_bounds__(192) void k_s2(const float* __restrict__ cumS,
                                            const float* __restrict__ A_logs,
                                            float* __restrict__ Hend) {
    __shared__ float LP[NCHUNK * SP2];   // pad 17 -> conflict-free stride
    __shared__ float LE[NCHUNK * SP2];
    int bid = blockIdx.x;                // 8 * 192
    int bk = bid / NCH, c = bid % NCH;
    int k = bk & 3;
    int j = threadIdx.x;                 // chunk index (j < 144 active)
    float A2[NN], P[NN], E[NN];
    size_t eb = 0;
    if (j < NCHUNK) {
        const float4* ap = (const float4*)(A_logs + ((size_t)(k * NCH + c)) * NN);
        float4 a0 = ap[0], a1 = ap[1], a2 = ap[2], a3 = ap[3];
        float t[16] = {a0.x, a0.y, a0.z, a0.w, a1.x, a1.y, a1.z, a1.w,
                       a2.x, a2.y, a2.z, a2.w, a3.x, a3.y, a3.z, a3.w};
#pragma unroll
        for (int n = 0; n < NN; ++n) A2[n] = -expf(t[n]) * 1.44269504f;
        float Sv = cumS[(size_t)bk * NL * NCH + (size_t)(j * CLEN + CLEN - 1) * NCH + c];
        eb = (((size_t)bk * NCHUNK + j) * NCH + c) * NN;
        const float4* hp = (const float4*)(Hend + eb);
        float4 e0 = hp[0], e1 = hp[1], e2 = hp[2], e3 = hp[3];
        float te[16] = {e0.x, e0.y, e0.z, e0.w, e1.x, e1.y, e1.z, e1.w,
                        e2.x, e2.y, e2.z, e2.w, e3.x, e3.y, e3.z, e3.w};
#pragma unroll
        for (int n = 0; n < NN; ++n) {
            E[n] = te[n];
            P[n] = exp2f(Sv * A2[n]);
            LP[j * SP2 + n] = P[n];
            LE[j * SP2 + n] = E[n];
        }
    }
    for (int s = 1; s < NCHUNK; s <<= 1) {   // 8 steps
        __syncthreads();
        float pe[NN], ee[NN];
        bool act = (j < NCHUNK) && (j >= s);
        if (act) {
#pragma unroll
            for (int n = 0; n < NN; ++n) {
                pe[n] = LP[(j - s) * SP2 + n];
                ee[n] = LE[(j - s) * SP2 + n];
            }
        }
        __syncthreads();
        if (act) {
#pragma unroll
            for (int n = 0; n < NN; ++n) {
                E[n] = fmaf(P[n], ee[n], E[n]);   // E = P_cur*E_left + E_cur
                P[n] = P[n] * pe[n];
                LP[j * SP2 + n] = P[n];
                LE[j * SP2 + n] = E[n];
            }
        }
    }
    __syncthreads();
    if (j < NCHUNK) {
        float o[NN];
        if (j == 0) {
#pragma unroll
            for (int n = 0; n < NN; ++n) o[n] = 0.0f;
        } else {
#pragma unroll
            for (int n = 0; n < NN; ++n) o[n] = LE[(j - 1) * SP2 + n];
        }
#pragma unroll
        for (int qq = 0; qq < 4; ++qq)
            *(float4*)&Hend[eb + qq * 4] =
                make_float4(o[qq*4], o[qq*4+1], o[qq*4+2], o[qq*4+3]);
    }
}

// -------- fix: y += C · (exp2(cumS·A2) ∘ h_in) — 384 threads, half-split l
__global__ __launch_bounds__(384) void k_fix(const float* __restrict__ Cbuf,
                                             const float* __restrict__ cumS,
                                             const float* __restrict__ Hin,
                                             const float* __restrict__ A_logs,
                                             float* __restrict__ ybuf) {
    int bid = blockIdx.x;                // 8 * 144
    int bk = bid / NLT;
    int chk = bid % NLT;
    int lt0 = chk * LTILE;
    int k = bk & 3;
    int tid = threadIdx.x;
    int half = (tid >= NCH) ? 1 : 0;
    int c = tid - half * NCH;
    int lb = half * HLEN;
    float A2[NN];
    {
        const float4* ap = (const float4*)(A_logs + ((size_t)(k * NCH + c)) * NN);
        float4 a0 = ap[0], a1 = ap[1], a2 = ap[2], a3 = ap[3];
        float t[16] = {a0.x, a0.y, a0.z, a0.w, a1.x, a1.y, a1.z, a1.w,
                       a2.x, a2.y, a2.z, a2.w, a3.x, a3.y, a3.z, a3.w};
#pragma unroll
        for (int n = 0; n < NN; ++n) A2[n] = -expf(t[n]) * 1.44269504f;
    }
    float hin[NN];
    {
        size_t ob = (((size_t)bk * NCHUNK + chk) * NCH + c) * NN;
        const float4* hp = (const float4*)(Hin + ob);
        float4 h0 = hp[0], h1 = hp[1], h2 = hp[2], h3 = hp[3];
        float t[16] = {h0.x, h0.y, h0.z, h0.w, h1.x, h1.y, h1.z, h1.w,
                       h2.x, h2.y, h2.z, h2.w, h3.x, h3.y, h3.z, h3.w};
#pragma unroll
        for (int n = 0; n < NN; ++n) hin[n] = t[n];
    }
    const float* csp = cumS + (size_t)bk * NL * NCH + c;
    float* yp = ybuf + (size_t)bk * NL * NCH + c;
#pragma unroll
    for (int i = 0; i < HLEN; ++i) {
        int l = lt0 + lb + i;
        float csv = csp[(size_t)l * NCH];
        const float4* cr = (const float4*)(Cbuf + ((size_t)bk * NL + l) * NN);
        float4 c0 = cr[0], c1 = cr[1], c2 = cr[2], c3 = cr[3];
        float Cv[16] = {c0.x, c0.y, c0.z, c0.w, c1.x, c1.y, c1.z, c1.w,
                        c2.x, c2.y, c2.z, c2.w, c3.x, c3.y, c3.z, c3.w};
        float corr = 0.0f;
#pragma unroll
        for (int n = 0; n < NN; ++n) {
            float e = exp2f(csv * A2[n]);
            corr = fmaf(Cv[n] * hin[n], e, corr);
        }
        yp[(size_t)l * NCH] += corr;
    }
}

// ------------------------------------------- cross-merge from [bk][l][c]
__global__ __launch_bounds__(256) void k_merge(const float* __restrict__ ybuf,
                                               float* __restrict__ out) {
    int b = blockIdx.x / NH;
    int hh = blockIdx.x % NH;
    __shared__ float tile[NW * 193];
    const float* Y0 = ybuf + (size_t)(b * NK + 0) * NL * NCH;
    const float* Y1 = ybuf + (size_t)(b * NK + 1) * NL * NCH;
    const float* Y2 = ybuf + (size_t)(b * NK + 2) * NL * NCH;
    const float* Y3 = ybuf + (size_t)(b * NK + 3) * NL * NCH;
    for (int i = threadIdx.x; i < NW * NCH; i += 256) {
        int w = i / NCH, c = i % NCH;
        int hw = hh * NW + w;
        int wh = w * NH + hh;
        float v = Y0[(size_t)hw * NCH + c]
                + Y2[(size_t)(NL - 1 - hw) * NCH + c]
                + Y1[(size_t)wh * NCH + c]
                + Y3[(size_t)(NL - 1 - wh) * NCH + c];
        tile[w * 193 + c] = v;
    }
    __syncthreads();
    for (int i = threadIdx.x; i < NW * NCH; i += 256) {
        int c = i / NW, w = i % NW;
        out[((size_t)(b * NCH + c)) * NL + hh * NW + w] = tile[w * 193 + c];
    }
}

extern "C" void kernel_launch(void* const* d_in, const int* in_sizes, int n_in,
                              void* d_out, int out_size, void* d_ws, size_t ws_size,
                              hipStream_t stream) {
    const float* x      = (const float*)d_in[0];
    const float* xpw    = (const float*)d_in[1];
    const float* dtw    = (const float*)d_in[2];
    const float* A_logs = (const float*)d_in[3];
    const float* Ds     = (const float*)d_in[4];
    const float* dtb    = (const float*)d_in[5];
    float* out = (float*)d_out;

    float* ws = (float*)d_ws;
    float* xT    = ws;
    float* ut0   = xT + SZ_XT;
    float* Cbuf  = ut0 + SZ_UT0;
    float* cumS  = Cbuf + SZ_CB;
    float* ybuf  = cumS + SZ_CUMS;
    float* Hend  = ybuf + SZ_YBUF;   // after k_s2 holds Hin (in-place)

    k_prep<<<NB * NCH + NB * 36, 256, 0, stream>>>(x, xT, ut0);
    k_projscan<<<NB * NK * NLT, 384, 0, stream>>>(x, xT, xpw, dtw, dtb, A_logs,
                                                  Ds, ut0, Cbuf, cumS, ybuf, Hend);
    k_s2<<<NB * NK * NCH, 192, 0, stream>>>(cumS, A_logs, Hend);
    k_fix<<<NB * NK * NLT, 384, 0, stream>>>(Cbuf, cumS, Hend, A_logs, ybuf);
    k_merge<<<NB * NH, 256, 0, stream>>>(ybuf, out);
}

// Round 2
// 169.718 us; speedup vs baseline: 1.2622x; 1.2622x over previous
//
#include <hip/hip_runtime.h>
#include <math.h>

#define NB 2
#define NCH 192
#define NH 48
#define NW 48
#define NL 2304
#define NK 4
#define NN 16
#define NR 12
#define ND 44
#define NCHUNK 144
#define CLEN 16                     // NL / NCHUNK
#define LTILE 16
#define NLT (NL / LTILE)            // 144 (== NCHUNK, tile == chunk)

// workspace float sizes
#define SZ_XT    (NB * NCH * NL)                 // 884736
#define SZ_UT0   (NB * NL * NCH)                 // 884736
#define SZ_CB    (NB * NK * NL * NN)             // 294912
#define SZ_CUMS  (NB * NK * NL * NCH)            // 3538944
#define SZ_YBUF  (NB * NK * NL * NCH)            // 3538944
#define SZ_HEND  (NB * NK * NCHUNK * NCH * NN)   // 3538944
#define SZ_A2    (NK * NCH * NN)                 // 12288

// --------------------------------------------- prep: xT + ut0 + A2 (one launch)
__global__ __launch_bounds__(256) void k_prep(const float* __restrict__ x,
                                              const float* __restrict__ A_logs,
                                              float* __restrict__ xT,
                                              float* __restrict__ ut0,
                                              float* __restrict__ A2buf) {
    __shared__ float tile[64 * 193];
    int bid = blockIdx.x;
    if (bid < NB * NCH) {
        // xT[b][c][w*48+h] = x[b][c][h*48+w]
        const float* src = x + (size_t)bid * NL;
        float* dst = xT + (size_t)bid * NL;
        for (int i = threadIdx.x; i < NL; i += 256) {
            int h = i / NW, w = i % NW;
            tile[w * 49 + h] = src[i];
        }
        __syncthreads();
        for (int i = threadIdx.x; i < NL; i += 256) {
            dst[i] = tile[i + i / NH];
        }
    } else if (bid < NB * NCH + NB * 36) {
        // ut0[b][l][c] = x[b][c][l]
        int t = bid - NB * NCH;                // 0..71
        int b = t / 36, lt = t % 36;
        int l0 = lt * 64;
        const float* bx = x + (size_t)b * NCH * NL;
        for (int i = threadIdx.x; i < NCH * 64; i += 256) {
            int c = i >> 6, j = i & 63;        // coalesced read along l
            tile[j * 193 + c] = bx[(size_t)c * NL + l0 + j];
        }
        __syncthreads();
        float* bo = ut0 + (size_t)b * NL * NCH;
        for (int i = threadIdx.x; i < NCH * 64; i += 256) {
            int j = i / NCH, c = i % NCH;      // coalesced write along c
            bo[(size_t)(l0 + j) * NCH + c] = tile[j * 193 + c];
        }
    } else {
        // A2buf[k][c][n] = -exp(A_logs) * log2(e)
        int t2 = bid - (NB * NCH + NB * 36);   // 0..11
        int i = t2 * 1024 + threadIdx.x;
        for (int q = 0; q < 4; ++q, i += 256)
            A2buf[i] = -expf(A_logs[i]) * 1.44269504f;
    }
}

__device__ __forceinline__ int u_row(int k, int l) {
    int pos = (k >= 2) ? (NL - 1 - l) : l;
    if (k & 1) pos = (pos % 48) * 48 + (pos / 48);
    return pos;
}

// ---- fused proj + delta + chunk-local scan emitting y_local.
// Outputs: Cbuf[bk][l][16], cumS[bk][l][c] (inclusive), ybuf[bk][l][c] (local y),
//          Hend[bk][ch][c][16] (chunk-local end state)
__global__ __launch_bounds__(192) void k_projscan(const float* __restrict__ x,
                                                  const float* __restrict__ xT,
                                                  const float* __restrict__ xpw,
                                                  const float* __restrict__ dtw,
                                                  const float* __restrict__ dt_bias,
                                                  const float* __restrict__ A2buf,
                                                  const float* __restrict__ Ds,
                                                  const float* __restrict__ ut0,
                                                  float* __restrict__ Cbuf,
                                                  float* __restrict__ cumS,
                                                  float* __restrict__ ybuf,
                                                  float* __restrict__ Hend) {
    int bid = blockIdx.x;                      // 8 * 144
    int bk = bid / NLT;
    int chk = bid % NLT;
    int lt0 = chk * LTILE;
    int b = bk >> 2, k = bk & 3;
    int tid = threadIdx.x;
    int lt = tid / ND;                         // 0..3 (l-group of 4), tid<176
    int dt = tid % ND;                         // 0..43
    __shared__ float WL[96 * 45];              // [cc][d] pad 45  17.3 KB
    __shared__ float XS[96 * LTILE];           // [cc][l]          6.1 KB
    __shared__ float DT[LTILE * NR];           // dts
    __shared__ float BL[LTILE * NN];           // B
    __shared__ float CL[LTILE * NN];           // C
    const float* bx = ((k & 1) ? xT : x) + (size_t)b * NCH * NL;
    bool rev = (k >= 2);
    int gbase = rev ? (NL - LTILE - lt0) : lt0;
    float acc[4] = {0.0f, 0.0f, 0.0f, 0.0f};
    for (int ph = 0; ph < 2; ++ph) {
        int c0 = ph * 96;
        __syncthreads();
        for (int i = tid; i < 96 * ND; i += 192) {
            int d = i / 96, cc = i % 96;       // coalesced along cc
            WL[cc * 45 + d] = xpw[((size_t)k * ND + d) * NCH + c0 + cc];
        }
        for (int i = tid; i < 96 * 4; i += 192) {
            int cc = i >> 2, q4 = i & 3;       // float4 per thread
            float4 v = *(const float4*)(bx + (size_t)(c0 + cc) * NL + gbase + q4 * 4);
            if (!rev) {
                *(float4*)&XS[cc * LTILE + q4 * 4] = v;
            } else {
                *(float4*)&XS[cc * LTILE + (3 - q4) * 4] =
                    make_float4(v.w, v.z, v.y, v.x);
            }
        }
        __syncthreads();
        if (tid < 4 * ND) {
#pragma unroll 8
            for (int cc = 0; cc < 96; ++cc) {
                float4 xv = *(const float4*)&XS[cc * LTILE + lt * 4];
                float wv = WL[cc * 45 + dt];
                acc[0] = fmaf(xv.x, wv, acc[0]);
                acc[1] = fmaf(xv.y, wv, acc[1]);
                acc[2] = fmaf(xv.z, wv, acc[2]);
                acc[3] = fmaf(xv.w, wv, acc[3]);
            }
        }
    }
    if (tid < 4 * ND) {
#pragma unroll
        for (int li = 0; li < 4; ++li) {
            int l = lt * 4 + li;               // within tile
            if (dt < NR) {
                DT[l * NR + dt] = acc[li];
            } else if (dt < NR + NN) {
                BL[l * NN + (dt - NR)] = acc[li];
            } else {
                CL[l * NN + (dt - NR - NN)] = acc[li];
                Cbuf[((size_t)bk * NL + lt0 + l) * NN + (dt - NR - NN)] = acc[li];
            }
        }
    }
    __syncthreads();
    // ------- tail: thread c does delta+softplus (ILP phase) then local scan
    int c = tid;
    float A2[NN];
    {
        const float4* ap = (const float4*)(A2buf + ((size_t)(k * NCH + c)) * NN);
        float4 a0 = ap[0], a1 = ap[1], a2 = ap[2], a3 = ap[3];
        A2[0]=a0.x; A2[1]=a0.y; A2[2]=a0.z; A2[3]=a0.w;
        A2[4]=a1.x; A2[5]=a1.y; A2[6]=a1.z; A2[7]=a1.w;
        A2[8]=a2.x; A2[9]=a2.y; A2[10]=a2.z; A2[11]=a2.w;
        A2[12]=a3.x; A2[13]=a3.y; A2[14]=a3.z; A2[15]=a3.w;
    }
    const float4* wp = (const float4*)(dtw + ((size_t)k * NCH + c) * NR);
    float4 w0 = wp[0], w1 = wp[1], w2 = wp[2];
    float bias = dt_bias[k * NCH + c];
    float dval = Ds[k * NCH + c];
    const float* up = ut0 + (size_t)b * NL * NCH + c;
    float* csp = cumS + (size_t)bk * NL * NCH + c;
    float sp[CLEN], uvv[CLEN];
    float S = 0.0f;
#pragma unroll
    for (int i = 0; i < CLEN; ++i) {
        int l = lt0 + i;
        float4 a0 = *(const float4*)&DT[i * NR + 0];
        float4 a1 = *(const float4*)&DT[i * NR + 4];
        float4 a2 = *(const float4*)&DT[i * NR + 8];
        float p0 = fmaf(w0.x, a0.x, fmaf(w0.y, a0.y, bias));
        float p1 = fmaf(w0.z, a0.z, w0.w * a0.w);
        float p2 = fmaf(w1.x, a1.x, fmaf(w1.y, a1.y, w1.z * a1.z));
        float p3 = fmaf(w1.w, a1.w, fmaf(w2.x, a2.x, w2.y * a2.y));
        float p4 = fmaf(w2.z, a2.z, w2.w * a2.w);
        float acc2 = (p0 + p1) + (p2 + p3) + p4;
        float s = fmaxf(acc2, 0.0f) + __logf(1.0f + __expf(-fabsf(acc2)));
        sp[i] = s;
        S += s;
        csp[(size_t)l * NCH] = S;
        uvv[i] = up[(size_t)u_row(k, l) * NCH];
    }
    float h[NN];
#pragma unroll
    for (int n = 0; n < NN; ++n) h[n] = 0.0f;
    float* yp = ybuf + (size_t)bk * NL * NCH + c;
#pragma unroll 4
    for (int i = 0; i < CLEN; ++i) {
        float du = sp[i] * uvv[i];
        const float4* br = (const float4*)&BL[i * NN];
        float4 b0 = br[0], b1 = br[1], b2 = br[2], b3 = br[3];
        float Bv[16] = {b0.x, b0.y, b0.z, b0.w, b1.x, b1.y, b1.z, b1.w,
                        b2.x, b2.y, b2.z, b2.w, b3.x, b3.y, b3.z, b3.w};
        const float4* cr = (const float4*)&CL[i * NN];
        float4 c0 = cr[0], c1 = cr[1], c2 = cr[2], c3 = cr[3];
        float Cv[16] = {c0.x, c0.y, c0.z, c0.w, c1.x, c1.y, c1.z, c1.w,
                        c2.x, c2.y, c2.z, c2.w, c3.x, c3.y, c3.z, c3.w};
        float y = 0.0f;
#pragma unroll
        for (int n = 0; n < NN; ++n) {
            float dA = exp2f(sp[i] * A2[n]);
            h[n] = fmaf(dA, h[n], du * Bv[n]);
            y = fmaf(h[n], Cv[n], y);
        }
        y = fmaf(dval, uvv[i], y);
        yp[(size_t)(lt0 + i) * NCH] = y;
    }
    size_t ob = (((size_t)bk * NCHUNK + chk) * NCH + c) * NN;
#pragma unroll
    for (int q = 0; q < 4; ++q)
        *(float4*)&Hend[ob + q * 4] =
            make_float4(h[q*4], h[q*4+1], h[q*4+2], h[q*4+3]);
}

// ------------- scan pass 2: parallel chunk prefix (Hillis-Steele in LDS).
// One block per (bk,c): thread j owns chunk j's (P,E) pair (16 n in regs).
// After this kernel Hend[j] holds the INCOMING state for chunk j.
#define SP2 17
__global__ __launch_bounds__(192) void k_s2(const float* __restrict__ cumS,
                                            const float* __restrict__ A2buf,
                                            float* __restrict__ Hend) {
    __shared__ float LP[NCHUNK * SP2];   // pad 17 -> conflict-free stride
    __shared__ float LE[NCHUNK * SP2];
    int bid = blockIdx.x;                // 8 * 192
    int bk = bid / NCH, c = bid % NCH;
    int k = bk & 3;
    int j = threadIdx.x;                 // chunk index (j < 144 active)
    float A2[NN], P[NN], E[NN];
    size_t eb = 0;
    if (j < NCHUNK) {
        const float4* ap = (const float4*)(A2buf + ((size_t)(k * NCH + c)) * NN);
        float4 a0 = ap[0], a1 = ap[1], a2 = ap[2], a3 = ap[3];
        float t[16] = {a0.x, a0.y, a0.z, a0.w, a1.x, a1.y, a1.z, a1.w,
                       a2.x, a2.y, a2.z, a2.w, a3.x, a3.y, a3.z, a3.w};
#pragma unroll
        for (int n = 0; n < NN; ++n) A2[n] = t[n];
        float Sv = cumS[(size_t)bk * NL * NCH + (size_t)(j * CLEN + CLEN - 1) * NCH + c];
        eb = (((size_t)bk * NCHUNK + j) * NCH + c) * NN;
        const float4* hp = (const float4*)(Hend + eb);
        float4 e0 = hp[0], e1 = hp[1], e2 = hp[2], e3 = hp[3];
        float te[16] = {e0.x, e0.y, e0.z, e0.w, e1.x, e1.y, e1.z, e1.w,
                        e2.x, e2.y, e2.z, e2.w, e3.x, e3.y, e3.z, e3.w};
#pragma unroll
        for (int n = 0; n < NN; ++n) {
            E[n] = te[n];
            P[n] = exp2f(Sv * A2[n]);
            LP[j * SP2 + n] = P[n];
            LE[j * SP2 + n] = E[n];
        }
    }
    for (int s = 1; s < NCHUNK; s <<= 1) {   // 8 steps
        __syncthreads();
        float pe[NN], ee[NN];
        bool act = (j < NCHUNK) && (j >= s);
        if (act) {
#pragma unroll
            for (int n = 0; n < NN; ++n) {
                pe[n] = LP[(j - s) * SP2 + n];
                ee[n] = LE[(j - s) * SP2 + n];
            }
        }
        __syncthreads();
        if (act) {
#pragma unroll
            for (int n = 0; n < NN; ++n) {
                E[n] = fmaf(P[n], ee[n], E[n]);   // E = P_cur*E_left + E_cur
                P[n] = P[n] * pe[n];
                LP[j * SP2 + n] = P[n];
                LE[j * SP2 + n] = E[n];
            }
        }
    }
    __syncthreads();
    if (j < NCHUNK) {
        float o[NN];
        if (j == 0) {
#pragma unroll
            for (int n = 0; n < NN; ++n) o[n] = 0.0f;
        } else {
#pragma unroll
            for (int n = 0; n < NN; ++n) o[n] = LE[(j - 1) * SP2 + n];
        }
#pragma unroll
        for (int qq = 0; qq < 4; ++qq)
            *(float4*)&Hend[eb + qq * 4] =
                make_float4(o[qq*4], o[qq*4+1], o[qq*4+2], o[qq*4+3]);
    }
}

// -------- fix: y += C · (exp2(cumS·A2) ∘ h_in)  — fully parallel, no syncs
__global__ __launch_bounds__(192) void k_fix(const float* __restrict__ Cbuf,
                                             const float* __restrict__ cumS,
                                             const float* __restrict__ Hin,
                                             const float* __restrict__ A2buf,
                                             float* __restrict__ ybuf) {
    int bid = blockIdx.x;                      // 8 * 144
    int bk = bid / NLT;
    int chk = bid % NLT;
    int lt0 = chk * LTILE;
    int k = bk & 3;
    int c = threadIdx.x;
    float A2[NN];
    {
        const float4* ap = (const float4*)(A2buf + ((size_t)(k * NCH + c)) * NN);
        float4 a0 = ap[0], a1 = ap[1], a2 = ap[2], a3 = ap[3];
        A2[0]=a0.x; A2[1]=a0.y; A2[2]=a0.z; A2[3]=a0.w;
        A2[4]=a1.x; A2[5]=a1.y; A2[6]=a1.z; A2[7]=a1.w;
        A2[8]=a2.x; A2[9]=a2.y; A2[10]=a2.z; A2[11]=a2.w;
        A2[12]=a3.x; A2[13]=a3.y; A2[14]=a3.z; A2[15]=a3.w;
    }
    float hin[NN];
    {
        size_t ob = (((size_t)bk * NCHUNK + chk) * NCH + c) * NN;
        const float4* hp = (const float4*)(Hin + ob);
        float4 h0 = hp[0], h1 = hp[1], h2 = hp[2], h3 = hp[3];
        float t[16] = {h0.x, h0.y, h0.z, h0.w, h1.x, h1.y, h1.z, h1.w,
                       h2.x, h2.y, h2.z, h2.w, h3.x, h3.y, h3.z, h3.w};
#pragma unroll
        for (int n = 0; n < NN; ++n) hin[n] = t[n];
    }
    const float* csp = cumS + (size_t)bk * NL * NCH + c;
    float* yp = ybuf + (size_t)bk * NL * NCH + c;
#pragma unroll 4
    for (int i = 0; i < CLEN; ++i) {
        int l = lt0 + i;
        float cs = csp[(size_t)l * NCH];
        const float4* cr = (const float4*)(Cbuf + ((size_t)bk * NL + l) * NN);
        float4 c0 = cr[0], c1 = cr[1], c2 = cr[2], c3 = cr[3];
        float Cv[16] = {c0.x, c0.y, c0.z, c0.w, c1.x, c1.y, c1.z, c1.w,
                        c2.x, c2.y, c2.z, c2.w, c3.x, c3.y, c3.z, c3.w};
        float corr = 0.0f;
#pragma unroll
        for (int n = 0; n < NN; ++n) {
            float e = exp2f(cs * A2[n]);
            corr = fmaf(Cv[n] * hin[n], e, corr);
        }
        yp[(size_t)l * NCH] += corr;
    }
}

// ------------------------------------------- cross-merge from [bk][l][c]
__global__ __launch_bounds__(256) void k_merge(const float* __restrict__ ybuf,
                                               float* __restrict__ out) {
    int b = blockIdx.x / NH;
    int hh = blockIdx.x % NH;
    __shared__ float tile[NW * 193];
    const float* Y0 = ybuf + (size_t)(b * NK + 0) * NL * NCH;
    const float* Y1 = ybuf + (size_t)(b * NK + 1) * NL * NCH;
    const float* Y2 = ybuf + (size_t)(b * NK + 2) * NL * NCH;
    const float* Y3 = ybuf + (size_t)(b * NK + 3) * NL * NCH;
    for (int i = threadIdx.x; i < NW * NCH; i += 256) {
        int w = i / NCH, c = i % NCH;
        int hw = hh * NW + w;
        int wh = w * NH + hh;
        float v = Y0[(size_t)hw * NCH + c]
                + Y2[(size_t)(NL - 1 - hw) * NCH + c]
                + Y1[(size_t)wh * NCH + c]
                + Y3[(size_t)(NL - 1 - wh) * NCH + c];
        tile[w * 193 + c] = v;
    }
    __syncthreads();
    for (int i = threadIdx.x; i < NW * NCH; i += 256) {
        int c = i / NW, w = i % NW;
        out[((size_t)(b * NCH + c)) * NL + hh * NW + w] = tile[w * 193 + c];
    }
}

extern "C" void kernel_launch(void* const* d_in, const int* in_sizes, int n_in,
                              void* d_out, int out_size, void* d_ws, size_t ws_size,
                              hipStream_t stream) {
    const float* x      = (const float*)d_in[0];
    const float* xpw    = (const float*)d_in[1];
    const float* dtw    = (const float*)d_in[2];
    const float* A_logs = (const float*)d_in[3];
    const float* Ds     = (const float*)d_in[4];
    const float* dtb    = (const float*)d_in[5];
    float* out = (float*)d_out;

    float* ws = (float*)d_ws;
    float* xT    = ws;
    float* ut0   = xT + SZ_XT;
    float* Cbuf  = ut0 + SZ_UT0;
    float* cumS  = Cbuf + SZ_CB;
    float* ybuf  = cumS + SZ_CUMS;
    float* Hend  = ybuf + SZ_YBUF;   // after k_s2 holds Hin (in-place)
    float* A2buf = Hend + SZ_HEND;

    k_prep<<<NB * NCH + NB * 36 + 12, 256, 0, stream>>>(x, A_logs, xT, ut0, A2buf);
    k_projscan<<<NB * NK * NLT, 192, 0, stream>>>(x, xT, xpw, dtw, dtb, A2buf,
                                                  Ds, ut0, Cbuf, cumS, ybuf, Hend);
    k_s2<<<NB * NK * NCH, 192, 0, stream>>>(cumS, A2buf, Hend);
    k_fix<<<NB * NK * NLT, 192, 0, stream>>>(Cbuf, cumS, Hend, A2buf, ybuf);
    k_merge<<<NB * NH, 256, 0, stream>>>(ybuf, out);
}

// Round 3
// 168.556 us; speedup vs baseline: 1.2709x; 1.0069x over previous
//
#include <hip/hip_runtime.h>
#include <math.h>

#define NB 2
#define NCH 192
#define NH 48
#define NW 48
#define NL 2304
#define NK 4
#define NN 16
#define NR 12
#define ND 44
#define NCHUNK 144
#define CLEN 16                     // NL / NCHUNK
#define LTILE 16
#define NLT (NL / LTILE)            // 144 (== NCHUNK, tile == chunk)

// workspace float sizes
#define SZ_XT    (NB * NCH * NL)                 // 884736
#define SZ_UT0   (NB * NL * NCH)                 // 884736
#define SZ_CB    (NB * NK * NL * NN)             // 294912
#define SZ_CUMS  (NB * NK * NL * NCH)            // 3538944
#define SZ_YBUF  (NB * NK * NL * NCH)            // 3538944
#define SZ_HEND  (NB * NK * NCHUNK * NCH * NN)   // 3538944
#define SZ_A2    (NK * NCH * NN)                 // 12288

// --------------------------------------------- prep: xT + ut0 + A2 (one launch)
__global__ __launch_bounds__(256) void k_prep(const float* __restrict__ x,
                                              const float* __restrict__ A_logs,
                                              float* __restrict__ xT,
                                              float* __restrict__ ut0,
                                              float* __restrict__ A2buf) {
    __shared__ float tile[64 * 193];
    int bid = blockIdx.x;
    if (bid < NB * NCH) {
        // xT[b][c][w*48+h] = x[b][c][h*48+w]
        const float* src = x + (size_t)bid * NL;
        float* dst = xT + (size_t)bid * NL;
        for (int i = threadIdx.x; i < NL; i += 256) {
            int h = i / NW, w = i % NW;
            tile[w * 49 + h] = src[i];
        }
        __syncthreads();
        for (int i = threadIdx.x; i < NL; i += 256) {
            dst[i] = tile[i + i / NH];
        }
    } else if (bid < NB * NCH + NB * 36) {
        // ut0[b][l][c] = x[b][c][l]
        int t = bid - NB * NCH;                // 0..71
        int b = t / 36, lt = t % 36;
        int l0 = lt * 64;
        const float* bx = x + (size_t)b * NCH * NL;
        for (int i = threadIdx.x; i < NCH * 64; i += 256) {
            int c = i >> 6, j = i & 63;        // coalesced read along l
            tile[j * 193 + c] = bx[(size_t)c * NL + l0 + j];
        }
        __syncthreads();
        float* bo = ut0 + (size_t)b * NL * NCH;
        for (int i = threadIdx.x; i < NCH * 64; i += 256) {
            int j = i / NCH, c = i % NCH;      // coalesced write along c
            bo[(size_t)(l0 + j) * NCH + c] = tile[j * 193 + c];
        }
    } else {
        // A2buf[k][c][n] = -exp(A_logs) * log2(e)
        int t2 = bid - (NB * NCH + NB * 36);   // 0..11
        int i = t2 * 1024 + threadIdx.x;
        for (int q = 0; q < 4; ++q, i += 256)
            A2buf[i] = -expf(A_logs[i]) * 1.44269504f;
    }
}

__device__ __forceinline__ int u_row(int k, int l) {
    int pos = (k >= 2) ? (NL - 1 - l) : l;
    if (k & 1) pos = (pos % 48) * 48 + (pos / 48);
    return pos;
}

// ---- fused proj + delta + chunk-local scan emitting y_local.
// Proj phase reads x DIRECTLY from global (L1/L2 broadcast across dt lanes)
// instead of staging into LDS — relieves the per-CU LDS issue pipe.
__global__ __launch_bounds__(192) void k_projscan(const float* __restrict__ x,
                                                  const float* __restrict__ xT,
                                                  const float* __restrict__ xpw,
                                                  const float* __restrict__ dtw,
                                                  const float* __restrict__ dt_bias,
                                                  const float* __restrict__ A2buf,
                                                  const float* __restrict__ Ds,
                                                  const float* __restrict__ ut0,
                                                  float* __restrict__ Cbuf,
                                                  float* __restrict__ cumS,
                                                  float* __restrict__ ybuf,
                                                  float* __restrict__ Hend) {
    int bid = blockIdx.x;                      // 8 * 144
    int bk = bid / NLT;
    int chk = bid % NLT;
    int lt0 = chk * LTILE;
    int b = bk >> 2, k = bk & 3;
    int tid = threadIdx.x;
    int lt = tid / ND;                         // 0..3 (l-group of 4), tid<176
    int dt = tid % ND;                         // 0..43
    __shared__ float WL[96 * 45];              // [cc][d] pad 45  17.3 KB
    __shared__ float DT[LTILE * NR];           // dts
    __shared__ float BL[LTILE * NN];           // B
    __shared__ float CL[LTILE * NN];           // C
    const float* bx = ((k & 1) ? xT : x) + (size_t)b * NCH * NL;
    bool rev = (k >= 2);
    int l0 = lt0 + lt * 4;
    int xoff = rev ? (NL - 4 - l0) : l0;       // 16B-aligned either way
    float acc[4] = {0.0f, 0.0f, 0.0f, 0.0f};
    for (int ph = 0; ph < 2; ++ph) {
        int c0 = ph * 96;
        __syncthreads();
        for (int i = tid; i < 96 * ND; i += 192) {
            int d = i / 96, cc = i % 96;       // coalesced along cc
            WL[cc * 45 + d] = xpw[((size_t)k * ND + d) * NCH + c0 + cc];
        }
        __syncthreads();
        if (tid < 4 * ND) {
            const float* xp = bx + (size_t)c0 * NL + xoff;
            if (!rev) {
#pragma unroll 8
                for (int cc = 0; cc < 96; ++cc) {
                    float4 xv = *(const float4*)(xp + (size_t)cc * NL);
                    float wv = WL[cc * 45 + dt];
                    acc[0] = fmaf(xv.x, wv, acc[0]);
                    acc[1] = fmaf(xv.y, wv, acc[1]);
                    acc[2] = fmaf(xv.z, wv, acc[2]);
                    acc[3] = fmaf(xv.w, wv, acc[3]);
                }
            } else {
#pragma unroll 8
                for (int cc = 0; cc < 96; ++cc) {
                    float4 xv = *(const float4*)(xp + (size_t)cc * NL);
                    float wv = WL[cc * 45 + dt];
                    acc[0] = fmaf(xv.w, wv, acc[0]);   // l0+0 lives at .w
                    acc[1] = fmaf(xv.z, wv, acc[1]);
                    acc[2] = fmaf(xv.y, wv, acc[2]);
                    acc[3] = fmaf(xv.x, wv, acc[3]);
                }
            }
        }
    }
    if (tid < 4 * ND) {
#pragma unroll
        for (int li = 0; li < 4; ++li) {
            int l = lt * 4 + li;               // within tile
            if (dt < NR) {
                DT[l * NR + dt] = acc[li];
            } else if (dt < NR + NN) {
                BL[l * NN + (dt - NR)] = acc[li];
            } else {
                CL[l * NN + (dt - NR - NN)] = acc[li];
                Cbuf[((size_t)bk * NL + lt0 + l) * NN + (dt - NR - NN)] = acc[li];
            }
        }
    }
    __syncthreads();
    // ------- tail: thread c does delta+softplus (ILP phase) then local scan
    int c = tid;
    float A2[NN];
    {
        const float4* ap = (const float4*)(A2buf + ((size_t)(k * NCH + c)) * NN);
        float4 a0 = ap[0], a1 = ap[1], a2 = ap[2], a3 = ap[3];
        A2[0]=a0.x; A2[1]=a0.y; A2[2]=a0.z; A2[3]=a0.w;
        A2[4]=a1.x; A2[5]=a1.y; A2[6]=a1.z; A2[7]=a1.w;
        A2[8]=a2.x; A2[9]=a2.y; A2[10]=a2.z; A2[11]=a2.w;
        A2[12]=a3.x; A2[13]=a3.y; A2[14]=a3.z; A2[15]=a3.w;
    }
    const float4* wp = (const float4*)(dtw + ((size_t)k * NCH + c) * NR);
    float4 w0 = wp[0], w1 = wp[1], w2 = wp[2];
    float bias = dt_bias[k * NCH + c];
    float dval = Ds[k * NCH + c];
    const float* up = ut0 + (size_t)b * NL * NCH + c;
    float* csp = cumS + (size_t)bk * NL * NCH + c;
    float sp[CLEN], uvv[CLEN];
    float S = 0.0f;
#pragma unroll
    for (int i = 0; i < CLEN; ++i) {
        int l = lt0 + i;
        float4 a0 = *(const float4*)&DT[i * NR + 0];
        float4 a1 = *(const float4*)&DT[i * NR + 4];
        float4 a2 = *(const float4*)&DT[i * NR + 8];
        float p0 = fmaf(w0.x, a0.x, fmaf(w0.y, a0.y, bias));
        float p1 = fmaf(w0.z, a0.z, w0.w * a0.w);
        float p2 = fmaf(w1.x, a1.x, fmaf(w1.y, a1.y, w1.z * a1.z));
        float p3 = fmaf(w1.w, a1.w, fmaf(w2.x, a2.x, w2.y * a2.y));
        float p4 = fmaf(w2.z, a2.z, w2.w * a2.w);
        float acc2 = (p0 + p1) + (p2 + p3) + p4;
        float s = fmaxf(acc2, 0.0f) + __logf(1.0f + __expf(-fabsf(acc2)));
        sp[i] = s;
        S += s;
        csp[(size_t)l * NCH] = S;
        uvv[i] = up[(size_t)u_row(k, l) * NCH];
    }
    float h[NN];
#pragma unroll
    for (int n = 0; n < NN; ++n) h[n] = 0.0f;
    float* yp = ybuf + (size_t)bk * NL * NCH + c;
#pragma unroll 4
    for (int i = 0; i < CLEN; ++i) {
        float du = sp[i] * uvv[i];
        const float4* br = (const float4*)&BL[i * NN];
        float4 b0 = br[0], b1 = br[1], b2 = br[2], b3 = br[3];
        float Bv[16] = {b0.x, b0.y, b0.z, b0.w, b1.x, b1.y, b1.z, b1.w,
                        b2.x, b2.y, b2.z, b2.w, b3.x, b3.y, b3.z, b3.w};
        const float4* cr = (const float4*)&CL[i * NN];
        float4 c0 = cr[0], c1 = cr[1], c2 = cr[2], c3 = cr[3];
        float Cv[16] = {c0.x, c0.y, c0.z, c0.w, c1.x, c1.y, c1.z, c1.w,
                        c2.x, c2.y, c2.z, c2.w, c3.x, c3.y, c3.z, c3.w};
        float y = 0.0f;
#pragma unroll
        for (int n = 0; n < NN; ++n) {
            float dA = exp2f(sp[i] * A2[n]);
            h[n] = fmaf(dA, h[n], du * Bv[n]);
            y = fmaf(h[n], Cv[n], y);
        }
        y = fmaf(dval, uvv[i], y);
        yp[(size_t)(lt0 + i) * NCH] = y;
    }
    size_t ob = (((size_t)bk * NCHUNK + chk) * NCH + c) * NN;
#pragma unroll
    for (int q = 0; q < 4; ++q)
        *(float4*)&Hend[ob + q * 4] =
            make_float4(h[q*4], h[q*4+1], h[q*4+2], h[q*4+3]);
}

// ------------- scan pass 2: parallel chunk prefix (Hillis-Steele in LDS).
#define SP2 17
__global__ __launch_bounds__(192) void k_s2(const float* __restrict__ cumS,
                                            const float* __restrict__ A2buf,
                                            float* __restrict__ Hend) {
    __shared__ float LP[NCHUNK * SP2];   // pad 17 -> conflict-free stride
    __shared__ float LE[NCHUNK * SP2];
    int bid = blockIdx.x;                // 8 * 192
    int bk = bid / NCH, c = bid % NCH;
    int k = bk & 3;
    int j = threadIdx.x;                 // chunk index (j < 144 active)
    float A2[NN], P[NN], E[NN];
    size_t eb = 0;
    if (j < NCHUNK) {
        const float4* ap = (const float4*)(A2buf + ((size_t)(k * NCH + c)) * NN);
        float4 a0 = ap[0], a1 = ap[1], a2 = ap[2], a3 = ap[3];
        float t[16] = {a0.x, a0.y, a0.z, a0.w, a1.x, a1.y, a1.z, a1.w,
                       a2.x, a2.y, a2.z, a2.w, a3.x, a3.y, a3.z, a3.w};
#pragma unroll
        for (int n = 0; n < NN; ++n) A2[n] = t[n];
        float Sv = cumS[(size_t)bk * NL * NCH + (size_t)(j * CLEN + CLEN - 1) * NCH + c];
        eb = (((size_t)bk * NCHUNK + j) * NCH + c) * NN;
        const float4* hp = (const float4*)(Hend + eb);
        float4 e0 = hp[0], e1 = hp[1], e2 = hp[2], e3 = hp[3];
        float te[16] = {e0.x, e0.y, e0.z, e0.w, e1.x, e1.y, e1.z, e1.w,
                        e2.x, e2.y, e2.z, e2.w, e3.x, e3.y, e3.z, e3.w};
#pragma unroll
        for (int n = 0; n < NN; ++n) {
            E[n] = te[n];
            P[n] = exp2f(Sv * A2[n]);
            LP[j * SP2 + n] = P[n];
            LE[j * SP2 + n] = E[n];
        }
    }
    for (int s = 1; s < NCHUNK; s <<= 1) {   // 8 steps
        __syncthreads();
        float pe[NN], ee[NN];
        bool act = (j < NCHUNK) && (j >= s);
        if (act) {
#pragma unroll
            for (int n = 0; n < NN; ++n) {
                pe[n] = LP[(j - s) * SP2 + n];
                ee[n] = LE[(j - s) * SP2 + n];
            }
        }
        __syncthreads();
        if (act) {
#pragma unroll
            for (int n = 0; n < NN; ++n) {
                E[n] = fmaf(P[n], ee[n], E[n]);   // E = P_cur*E_left + E_cur
                P[n] = P[n] * pe[n];
                LP[j * SP2 + n] = P[n];
                LE[j * SP2 + n] = E[n];
            }
        }
    }
    __syncthreads();
    if (j < NCHUNK) {
        float o[NN];
        if (j == 0) {
#pragma unroll
            for (int n = 0; n < NN; ++n) o[n] = 0.0f;
        } else {
#pragma unroll
            for (int n = 0; n < NN; ++n) o[n] = LE[(j - 1) * SP2 + n];
        }
#pragma unroll
        for (int qq = 0; qq < 4; ++qq)
            *(float4*)&Hend[eb + qq * 4] =
                make_float4(o[qq*4], o[qq*4+1], o[qq*4+2], o[qq*4+3]);
    }
}

// -------- fix: y += C · (exp2(cumS·A2) ∘ h_in) — split into 8-l half-chunks
__global__ __launch_bounds__(192) void k_fix(const float* __restrict__ Cbuf,
                                             const float* __restrict__ cumS,
                                             const float* __restrict__ Hin,
                                             const float* __restrict__ A2buf,
                                             float* __restrict__ ybuf) {
    int bid = blockIdx.x;                      // 8 * 288
    int bk = bid / (NLT * 2);
    int r = bid % (NLT * 2);
    int chk = r >> 1, hf = r & 1;
    int lt0 = chk * LTILE + hf * 8;
    int k = bk & 3;
    int c = threadIdx.x;
    float A2[NN];
    {
        const float4* ap = (const float4*)(A2buf + ((size_t)(k * NCH + c)) * NN);
        float4 a0 = ap[0], a1 = ap[1], a2 = ap[2], a3 = ap[3];
        A2[0]=a0.x; A2[1]=a0.y; A2[2]=a0.z; A2[3]=a0.w;
        A2[4]=a1.x; A2[5]=a1.y; A2[6]=a1.z; A2[7]=a1.w;
        A2[8]=a2.x; A2[9]=a2.y; A2[10]=a2.z; A2[11]=a2.w;
        A2[12]=a3.x; A2[13]=a3.y; A2[14]=a3.z; A2[15]=a3.w;
    }
    float hin[NN];
    {
        size_t ob = (((size_t)bk * NCHUNK + chk) * NCH + c) * NN;
        const float4* hp = (const float4*)(Hin + ob);
        float4 h0 = hp[0], h1 = hp[1], h2 = hp[2], h3 = hp[3];
        float t[16] = {h0.x, h0.y, h0.z, h0.w, h1.x, h1.y, h1.z, h1.w,
                       h2.x, h2.y, h2.z, h2.w, h3.x, h3.y, h3.z, h3.w};
#pragma unroll
        for (int n = 0; n < NN; ++n) hin[n] = t[n];
    }
    const float* csp = cumS + (size_t)bk * NL * NCH + c;
    float* yp = ybuf + (size_t)bk * NL * NCH + c;
#pragma unroll
    for (int i = 0; i < 8; ++i) {
        int l = lt0 + i;
        float cs = csp[(size_t)l * NCH];
        const float4* cr = (const float4*)(Cbuf + ((size_t)bk * NL + l) * NN);
        float4 c0 = cr[0], c1 = cr[1], c2 = cr[2], c3 = cr[3];
        float Cv[16] = {c0.x, c0.y, c0.z, c0.w, c1.x, c1.y, c1.z, c1.w,
                        c2.x, c2.y, c2.z, c2.w, c3.x, c3.y, c3.z, c3.w};
        float corr = 0.0f;
#pragma unroll
        for (int n = 0; n < NN; ++n) {
            float e = exp2f(cs * A2[n]);
            corr = fmaf(Cv[n] * hin[n], e, corr);
        }
        yp[(size_t)l * NCH] += corr;
    }
}

// ------------------------------------------- cross-merge, split ×4 over c
__global__ __launch_bounds__(256) void k_merge(const float* __restrict__ ybuf,
                                               float* __restrict__ out) {
    int bid = blockIdx.x;                // NB * NH * 4 = 384
    int b = bid / (NH * 4);
    int r = bid % (NH * 4);
    int hh = r >> 2, cq = r & 3;
    int cbase = cq * 48;
    __shared__ float tile[NW * 49];
    const float* Y0 = ybuf + (size_t)(b * NK + 0) * NL * NCH;
    const float* Y1 = ybuf + (size_t)(b * NK + 1) * NL * NCH;
    const float* Y2 = ybuf + (size_t)(b * NK + 2) * NL * NCH;
    const float* Y3 = ybuf + (size_t)(b * NK + 3) * NL * NCH;
    for (int i = threadIdx.x; i < NW * 48; i += 256) {
        int w = i / 48, cs = i % 48;
        int c = cbase + cs;
        int hw = hh * NW + w;
        int wh = w * NH + hh;
        float v = Y0[(size_t)hw * NCH + c]
                + Y2[(size_t)(NL - 1 - hw) * NCH + c]
                + Y1[(size_t)wh * NCH + c]
                + Y3[(size_t)(NL - 1 - wh) * NCH + c];
        tile[w * 49 + cs] = v;
    }
    __syncthreads();
    for (int i = threadIdx.x; i < NW * 48; i += 256) {
        int cs = i / NW, w = i % NW;
        out[((size_t)(b * NCH + cbase + cs)) * NL + hh * NW + w] = tile[w * 49 + cs];
    }
}

extern "C" void kernel_launch(void* const* d_in, const int* in_sizes, int n_in,
                              void* d_out, int out_size, void* d_ws, size_t ws_size,
                              hipStream_t stream) {
    const float* x      = (const float*)d_in[0];
    const float* xpw    = (const float*)d_in[1];
    const float* dtw    = (const float*)d_in[2];
    const float* A_logs = (const float*)d_in[3];
    const float* Ds     = (const float*)d_in[4];
    const float* dtb    = (const float*)d_in[5];
    float* out = (float*)d_out;

    float* ws = (float*)d_ws;
    float* xT    = ws;
    float* ut0   = xT + SZ_XT;
    float* Cbuf  = ut0 + SZ_UT0;
    float* cumS  = Cbuf + SZ_CB;
    float* ybuf  = cumS + SZ_CUMS;
    float* Hend  = ybuf + SZ_YBUF;   // after k_s2 holds Hin (in-place)
    float* A2buf = Hend + SZ_HEND;

    k_prep<<<NB * NCH + NB * 36 + 12, 256, 0, stream>>>(x, A_logs, xT, ut0, A2buf);
    k_projscan<<<NB * NK * NLT, 192, 0, stream>>>(x, xT, xpw, dtw, dtb, A2buf,
                                                  Ds, ut0, Cbuf, cumS, ybuf, Hend);
    k_s2<<<NB * NK * NCH, 192, 0, stream>>>(cumS, A2buf, Hend);
    k_fix<<<NB * NK * NLT * 2, 192, 0, stream>>>(Cbuf, cumS, Hend, A2buf, ybuf);
    k_merge<<<NB * NH * 4, 256, 0, stream>>>(ybuf, out);
}

// Round 4
// 161.844 us; speedup vs baseline: 1.3236x; 1.0415x over previous
//
#include <hip/hip_runtime.h>
#include <math.h>

#define NB 2
#define NCH 192
#define NH 48
#define NW 48
#define NL 2304
#define NK 4
#define NN 16
#define NR 12
#define ND 44
#define NCHUNK 144
#define CLEN 16                     // NL / NCHUNK
#define LTILE 16
#define NLT (NL / LTILE)            // 144 (== NCHUNK, tile == chunk)

// workspace float sizes
#define SZ_XT    (NB * NCH * NL)                 // 884736
#define SZ_UT0   (NB * NL * NCH)                 // 884736
#define SZ_CB    (NB * NK * NL * NN)             // 294912
#define SZ_CUMS  (NB * NK * NL * NCH)            // 3538944
#define SZ_YBUF  (NB * NK * NL * NCH)            // 3538944
#define SZ_HEND  (NB * NK * NCHUNK * NCH * NN)   // 3538944
#define SZ_A2    (NK * NCH * NN)                 // 12288

// --------------------------------------------- prep: xT + ut0 + A2 (one launch)
__global__ __launch_bounds__(256) void k_prep(const float* __restrict__ x,
                                              const float* __restrict__ A_logs,
                                              float* __restrict__ xT,
                                              float* __restrict__ ut0,
                                              float* __restrict__ A2buf) {
    __shared__ float tile[64 * 193];
    int bid = blockIdx.x;
    if (bid < NB * NCH) {
        // xT[b][c][w*48+h] = x[b][c][h*48+w]
        const float* src = x + (size_t)bid * NL;
        float* dst = xT + (size_t)bid * NL;
        for (int i = threadIdx.x; i < NL; i += 256) {
            int h = i / NW, w = i % NW;
            tile[w * 49 + h] = src[i];
        }
        __syncthreads();
        for (int i = threadIdx.x; i < NL; i += 256) {
            dst[i] = tile[i + i / NH];
        }
    } else if (bid < NB * NCH + NB * 36) {
        // ut0[b][l][c] = x[b][c][l]
        int t = bid - NB * NCH;                // 0..71
        int b = t / 36, lt = t % 36;
        int l0 = lt * 64;
        const float* bx = x + (size_t)b * NCH * NL;
        for (int i = threadIdx.x; i < NCH * 64; i += 256) {
            int c = i >> 6, j = i & 63;        // coalesced read along l
            tile[j * 193 + c] = bx[(size_t)c * NL + l0 + j];
        }
        __syncthreads();
        float* bo = ut0 + (size_t)b * NL * NCH;
        for (int i = threadIdx.x; i < NCH * 64; i += 256) {
            int j = i / NCH, c = i % NCH;      // coalesced write along c
            bo[(size_t)(l0 + j) * NCH + c] = tile[j * 193 + c];
        }
    } else {
        // A2buf[k][c][n] = -exp(A_logs) * log2(e)
        int t2 = bid - (NB * NCH + NB * 36);   // 0..11
        int i = t2 * 1024 + threadIdx.x;
        for (int q = 0; q < 4; ++q, i += 256)
            A2buf[i] = -expf(A_logs[i]) * 1.44269504f;
    }
}

__device__ __forceinline__ int u_row(int k, int l) {
    int pos = (k >= 2) ? (NL - 1 - l) : l;
    if (k & 1) pos = (pos % 48) * 48 + (pos / 48);
    return pos;
}

// ---- fused proj + delta + chunk-local scan emitting y_local.
// Proj phase: each thread computes a 4d x 4l tile per cc-iteration from two
// dense ds_read_b128 (16 fma per 2 LDS reads instead of 4 per 2) — the proj
// phase was LDS-issue-pipe bound. 4-way cc-split + LDS partial reduction.
// WL rows: pad 52 + mod-13 segment rotation (bank spread for staging writes
// and strided reads). XS rows: pad 20 (conflict-free with strided cc).
#define WLP 52
#define XSP 20
#define PACCP 5
__global__ __launch_bounds__(192) void k_projscan(const float* __restrict__ x,
                                                  const float* __restrict__ xT,
                                                  const float* __restrict__ xpw,
                                                  const float* __restrict__ dtw,
                                                  const float* __restrict__ dt_bias,
                                                  const float* __restrict__ A2buf,
                                                  const float* __restrict__ Ds,
                                                  const float* __restrict__ ut0,
                                                  float* __restrict__ Cbuf,
                                                  float* __restrict__ cumS,
                                                  float* __restrict__ ybuf,
                                                  float* __restrict__ Hend) {
    int bid = blockIdx.x;                      // 8 * 144
    int bk = bid / NLT;
    int chk = bid % NLT;
    int lt0 = chk * LTILE;
    int b = bk >> 2, k = bk & 3;
    int tid = threadIdx.x;
    __shared__ float WL[96 * WLP];             // rotated-seg weights  20.0 KB
    __shared__ float XS[96 * XSP];             // [cc][l] pad 20        7.7 KB
    __shared__ float DT[LTILE * NR];           // dts
    __shared__ float BL[LTILE * NN];           // B
    __shared__ float CL[LTILE * NN];           // C
    float* PACC = WL;                          // alias: [l16][d44][sp4] pad 5
    const float* bx = ((k & 1) ? xT : x) + (size_t)b * NCH * NL;
    bool rev = (k >= 2);
    int gbase = rev ? (NL - LTILE - lt0) : lt0;

    // thread mapping for proj: dg (d-group of 4) x lg (l-group of 4) x sp (cc-split)
    int dg = tid % 11;                         // 0..10
    int rr = tid / 11;                         // 0..16
    int lg = rr & 3;                           // 0..3
    int sp = rr >> 2;                          // 0..3
    float acc[4][4] = {};
    for (int ph = 0; ph < 2; ++ph) {
        int c0 = ph * 96;
        __syncthreads();
        for (int i = tid; i < 96 * ND; i += 192) {
            int d = i / 96, cc = i % 96;       // coalesced along cc
            int seg = d >> 2;
            int rot = seg + cc;                // (seg+cc) % 13, rot <= 105
            int q = (rot * 5042) >> 16;
            rot -= q * 13;
            WL[cc * WLP + rot * 4 + (d & 3)] =
                xpw[((size_t)k * ND + d) * NCH + c0 + cc];
        }
        for (int i = tid; i < 96 * 4; i += 192) {
            int cc = i >> 2, q4 = i & 3;       // float4 per thread
            float4 v = *(const float4*)(bx + (size_t)(c0 + cc) * NL + gbase + q4 * 4);
            if (!rev) {
                *(float4*)&XS[cc * XSP + q4 * 4] = v;
            } else {
                *(float4*)&XS[cc * XSP + (3 - q4) * 4] =
                    make_float4(v.w, v.z, v.y, v.x);
            }
        }
        __syncthreads();
        if (tid < 176) {
            int segr = dg + sp;                // (dg + cc0) % 13 with cc0 = sp
            if (segr >= 13) segr -= 13;
#pragma unroll 8
            for (int ii = 0; ii < 24; ++ii) {
                int cc = 4 * ii + sp;
                float4 wv = *(const float4*)&WL[cc * WLP + segr * 4];
                float4 xv = *(const float4*)&XS[cc * XSP + lg * 4];
                float xa[4] = {xv.x, xv.y, xv.z, xv.w};
                float wa[4] = {wv.x, wv.y, wv.z, wv.w};
#pragma unroll
                for (int li = 0; li < 4; ++li)
#pragma unroll
                    for (int dd = 0; dd < 4; ++dd)
                        acc[li][dd] = fmaf(xa[li], wa[dd], acc[li][dd]);
                segr += 4;
                segr = (segr >= 13) ? segr - 13 : segr;
            }
        }
    }
    __syncthreads();                           // WL dead -> PACC
    if (tid < 176) {
#pragma unroll
        for (int li = 0; li < 4; ++li)
#pragma unroll
            for (int dd = 0; dd < 4; ++dd) {
                int l = lg * 4 + li, d = dg * 4 + dd;
                PACC[(l * ND + d) * PACCP + sp] = acc[li][dd];
            }
    }
    __syncthreads();
    if (tid < 176) {
        int lt = tid / ND, dt = tid % ND;
#pragma unroll
        for (int li = 0; li < 4; ++li) {
            int l = lt * 4 + li;               // within tile
            const float* pp = &PACC[(l * ND + dt) * PACCP];
            float v = (pp[0] + pp[1]) + (pp[2] + pp[3]);
            if (dt < NR) {
                DT[l * NR + dt] = v;
            } else if (dt < NR + NN) {
                BL[l * NN + (dt - NR)] = v;
            } else {
                CL[l * NN + (dt - NR - NN)] = v;
                Cbuf[((size_t)bk * NL + lt0 + l) * NN + (dt - NR - NN)] = v;
            }
        }
    }
    __syncthreads();
    // ------- tail: thread c does delta+softplus (ILP phase) then local scan
    int c = tid;
    float A2[NN];
    {
        const float4* ap = (const float4*)(A2buf + ((size_t)(k * NCH + c)) * NN);
        float4 a0 = ap[0], a1 = ap[1], a2 = ap[2], a3 = ap[3];
        A2[0]=a0.x; A2[1]=a0.y; A2[2]=a0.z; A2[3]=a0.w;
        A2[4]=a1.x; A2[5]=a1.y; A2[6]=a1.z; A2[7]=a1.w;
        A2[8]=a2.x; A2[9]=a2.y; A2[10]=a2.z; A2[11]=a2.w;
        A2[12]=a3.x; A2[13]=a3.y; A2[14]=a3.z; A2[15]=a3.w;
    }
    const float4* wp = (const float4*)(dtw + ((size_t)k * NCH + c) * NR);
    float4 w0 = wp[0], w1 = wp[1], w2 = wp[2];
    float bias = dt_bias[k * NCH + c];
    float dval = Ds[k * NCH + c];
    const float* up = ut0 + (size_t)b * NL * NCH + c;
    float* csp = cumS + (size_t)bk * NL * NCH + c;
    float sp_[CLEN], uvv[CLEN];
    float S = 0.0f;
#pragma unroll
    for (int i = 0; i < CLEN; ++i) {
        int l = lt0 + i;
        float4 a0 = *(const float4*)&DT[i * NR + 0];
        float4 a1 = *(const float4*)&DT[i * NR + 4];
        float4 a2 = *(const float4*)&DT[i * NR + 8];
        float p0 = fmaf(w0.x, a0.x, fmaf(w0.y, a0.y, bias));
        float p1 = fmaf(w0.z, a0.z, w0.w * a0.w);
        float p2 = fmaf(w1.x, a1.x, fmaf(w1.y, a1.y, w1.z * a1.z));
        float p3 = fmaf(w1.w, a1.w, fmaf(w2.x, a2.x, w2.y * a2.y));
        float p4 = fmaf(w2.z, a2.z, w2.w * a2.w);
        float acc2 = (p0 + p1) + (p2 + p3) + p4;
        float s = fmaxf(acc2, 0.0f) + __logf(1.0f + __expf(-fabsf(acc2)));
        sp_[i] = s;
        S += s;
        csp[(size_t)l * NCH] = S;
        uvv[i] = up[(size_t)u_row(k, l) * NCH];
    }
    float h[NN];
#pragma unroll
    for (int n = 0; n < NN; ++n) h[n] = 0.0f;
    float* yp = ybuf + (size_t)bk * NL * NCH + c;
#pragma unroll 4
    for (int i = 0; i < CLEN; ++i) {
        float du = sp_[i] * uvv[i];
        const float4* br = (const float4*)&BL[i * NN];
        float4 b0 = br[0], b1 = br[1], b2 = br[2], b3 = br[3];
        float Bv[16] = {b0.x, b0.y, b0.z, b0.w, b1.x, b1.y, b1.z, b1.w,
                        b2.x, b2.y, b2.z, b2.w, b3.x, b3.y, b3.z, b3.w};
        const float4* cr = (const float4*)&CL[i * NN];
        float4 c0 = cr[0], c1 = cr[1], c2 = cr[2], c3 = cr[3];
        float Cv[16] = {c0.x, c0.y, c0.z, c0.w, c1.x, c1.y, c1.z, c1.w,
                        c2.x, c2.y, c2.z, c2.w, c3.x, c3.y, c3.z, c3.w};
        float y = 0.0f;
#pragma unroll
        for (int n = 0; n < NN; ++n) {
            float dA = exp2f(sp_[i] * A2[n]);
            h[n] = fmaf(dA, h[n], du * Bv[n]);
            y = fmaf(h[n], Cv[n], y);
        }
        y = fmaf(dval, uvv[i], y);
        yp[(size_t)(lt0 + i) * NCH] = y;
    }
    size_t ob = (((size_t)bk * NCHUNK + chk) * NCH + c) * NN;
#pragma unroll
    for (int q = 0; q < 4; ++q)
        *(float4*)&Hend[ob + q * 4] =
            make_float4(h[q*4], h[q*4+1], h[q*4+2], h[q*4+3]);
}

// ------------- scan pass 2: parallel chunk prefix (Hillis-Steele in LDS).
#define SP2 17
__global__ __launch_bounds__(192) void k_s2(const float* __restrict__ cumS,
                                            const float* __restrict__ A2buf,
                                            float* __restrict__ Hend) {
    __shared__ float LP[NCHUNK * SP2];   // pad 17 -> conflict-free stride
    __shared__ float LE[NCHUNK * SP2];
    int bid = blockIdx.x;                // 8 * 192
    int bk = bid / NCH, c = bid % NCH;
    int k = bk & 3;
    int j = threadIdx.x;                 // chunk index (j < 144 active)
    float A2[NN], P[NN], E[NN];
    size_t eb = 0;
    if (j < NCHUNK) {
        const float4* ap = (const float4*)(A2buf + ((size_t)(k * NCH + c)) * NN);
        float4 a0 = ap[0], a1 = ap[1], a2 = ap[2], a3 = ap[3];
        float t[16] = {a0.x, a0.y, a0.z, a0.w, a1.x, a1.y, a1.z, a1.w,
                       a2.x, a2.y, a2.z, a2.w, a3.x, a3.y, a3.z, a3.w};
#pragma unroll
        for (int n = 0; n < NN; ++n) A2[n] = t[n];
        float Sv = cumS[(size_t)bk * NL * NCH + (size_t)(j * CLEN + CLEN - 1) * NCH + c];
        eb = (((size_t)bk * NCHUNK + j) * NCH + c) * NN;
        const float4* hp = (const float4*)(Hend + eb);
        float4 e0 = hp[0], e1 = hp[1], e2 = hp[2], e3 = hp[3];
        float te[16] = {e0.x, e0.y, e0.z, e0.w, e1.x, e1.y, e1.z, e1.w,
                        e2.x, e2.y, e2.z, e2.w, e3.x, e3.y, e3.z, e3.w};
#pragma unroll
        for (int n = 0; n < NN; ++n) {
            E[n] = te[n];
            P[n] = exp2f(Sv * A2[n]);
            LP[j * SP2 + n] = P[n];
            LE[j * SP2 + n] = E[n];
        }
    }
    for (int s = 1; s < NCHUNK; s <<= 1) {   // 8 steps
        __syncthreads();
        float pe[NN], ee[NN];
        bool act = (j < NCHUNK) && (j >= s);
        if (act) {
#pragma unroll
            for (int n = 0; n < NN; ++n) {
                pe[n] = LP[(j - s) * SP2 + n];
                ee[n] = LE[(j - s) * SP2 + n];
            }
        }
        __syncthreads();
        if (act) {
#pragma unroll
            for (int n = 0; n < NN; ++n) {
                E[n] = fmaf(P[n], ee[n], E[n]);   // E = P_cur*E_left + E_cur
                P[n] = P[n] * pe[n];
                LP[j * SP2 + n] = P[n];
                LE[j * SP2 + n] = E[n];
            }
        }
    }
    __syncthreads();
    if (j < NCHUNK) {
        float o[NN];
        if (j == 0) {
#pragma unroll
            for (int n = 0; n < NN; ++n) o[n] = 0.0f;
        } else {
#pragma unroll
            for (int n = 0; n < NN; ++n) o[n] = LE[(j - 1) * SP2 + n];
        }
#pragma unroll
        for (int qq = 0; qq < 4; ++qq)
            *(float4*)&Hend[eb + qq * 4] =
                make_float4(o[qq*4], o[qq*4+1], o[qq*4+2], o[qq*4+3]);
    }
}

// -------- fix: y += C · (exp2(cumS·A2) ∘ h_in) — split into 8-l half-chunks
__global__ __launch_bounds__(192) void k_fix(const float* __restrict__ Cbuf,
                                             const float* __restrict__ cumS,
                                             const float* __restrict__ Hin,
                                             const float* __restrict__ A2buf,
                                             float* __restrict__ ybuf) {
    int bid = blockIdx.x;                      // 8 * 288
    int bk = bid / (NLT * 2);
    int r = bid % (NLT * 2);
    int chk = r >> 1, hf = r & 1;
    int lt0 = chk * LTILE + hf * 8;
    int k = bk & 3;
    int c = threadIdx.x;
    float A2[NN];
    {
        const float4* ap = (const float4*)(A2buf + ((size_t)(k * NCH + c)) * NN);
        float4 a0 = ap[0], a1 = ap[1], a2 = ap[2], a3 = ap[3];
        A2[0]=a0.x; A2[1]=a0.y; A2[2]=a0.z; A2[3]=a0.w;
        A2[4]=a1.x; A2[5]=a1.y; A2[6]=a1.z; A2[7]=a1.w;
        A2[8]=a2.x; A2[9]=a2.y; A2[10]=a2.z; A2[11]=a2.w;
        A2[12]=a3.x; A2[13]=a3.y; A2[14]=a3.z; A2[15]=a3.w;
    }
    float hin[NN];
    {
        size_t ob = (((size_t)bk * NCHUNK + chk) * NCH + c) * NN;
        const float4* hp = (const float4*)(Hin + ob);
        float4 h0 = hp[0], h1 = hp[1], h2 = hp[2], h3 = hp[3];
        float t[16] = {h0.x, h0.y, h0.z, h0.w, h1.x, h1.y, h1.z, h1.w,
                       h2.x, h2.y, h2.z, h2.w, h3.x, h3.y, h3.z, h3.w};
#pragma unroll
        for (int n = 0; n < NN; ++n) hin[n] = t[n];
    }
    const float* csp = cumS + (size_t)bk * NL * NCH + c;
    float* yp = ybuf + (size_t)bk * NL * NCH + c;
#pragma unroll
    for (int i = 0; i < 8; ++i) {
        int l = lt0 + i;
        float cs = csp[(size_t)l * NCH];
        const float4* cr = (const float4*)(Cbuf + ((size_t)bk * NL + l) * NN);
        float4 c0 = cr[0], c1 = cr[1], c2 = cr[2], c3 = cr[3];
        float Cv[16] = {c0.x, c0.y, c0.z, c0.w, c1.x, c1.y, c1.z, c1.w,
                        c2.x, c2.y, c2.z, c2.w, c3.x, c3.y, c3.z, c3.w};
        float corr = 0.0f;
#pragma unroll
        for (int n = 0; n < NN; ++n) {
            float e = exp2f(cs * A2[n]);
            corr = fmaf(Cv[n] * hin[n], e, corr);
        }
        yp[(size_t)l * NCH] += corr;
    }
}

// ------------------------------------------- cross-merge, split ×4 over c
__global__ __launch_bounds__(256) void k_merge(const float* __restrict__ ybuf,
                                               float* __restrict__ out) {
    int bid = blockIdx.x;                // NB * NH * 4 = 384
    int b = bid / (NH * 4);
    int r = bid % (NH * 4);
    int hh = r >> 2, cq = r & 3;
    int cbase = cq * 48;
    __shared__ float tile[NW * 49];
    const float* Y0 = ybuf + (size_t)(b * NK + 0) * NL * NCH;
    const float* Y1 = ybuf + (size_t)(b * NK + 1) * NL * NCH;
    const float* Y2 = ybuf + (size_t)(b * NK + 2) * NL * NCH;
    const float* Y3 = ybuf + (size_t)(b * NK + 3) * NL * NCH;
    for (int i = threadIdx.x; i < NW * 48; i += 256) {
        int w = i / 48, cs = i % 48;
        int c = cbase + cs;
        int hw = hh * NW + w;
        int wh = w * NH + hh;
        float v = Y0[(size_t)hw * NCH + c]
                + Y2[(size_t)(NL - 1 - hw) * NCH + c]
                + Y1[(size_t)wh * NCH + c]
                + Y3[(size_t)(NL - 1 - wh) * NCH + c];
        tile[w * 49 + cs] = v;
    }
    __syncthreads();
    for (int i = threadIdx.x; i < NW * 48; i += 256) {
        int cs = i / NW, w = i % NW;
        out[((size_t)(b * NCH + cbase + cs)) * NL + hh * NW + w] = tile[w * 49 + cs];
    }
}

extern "C" void kernel_launch(void* const* d_in, const int* in_sizes, int n_in,
                              void* d_out, int out_size, void* d_ws, size_t ws_size,
                              hipStream_t stream) {
    const float* x      = (const float*)d_in[0];
    const float* xpw    = (const float*)d_in[1];
    const float* dtw    = (const float*)d_in[2];
    const float* A_logs = (const float*)d_in[3];
    const float* Ds     = (const float*)d_in[4];
    const float* dtb    = (const float*)d_in[5];
    float* out = (float*)d_out;

    float* ws = (float*)d_ws;
    float* xT    = ws;
    float* ut0   = xT + SZ_XT;
    float* Cbuf  = ut0 + SZ_UT0;
    float* cumS  = Cbuf + SZ_CB;
    float* ybuf  = cumS + SZ_CUMS;
    float* Hend  = ybuf + SZ_YBUF;   // after k_s2 holds Hin (in-place)
    float* A2buf = Hend + SZ_HEND;

    k_prep<<<NB * NCH + NB * 36 + 12, 256, 0, stream>>>(x, A_logs, xT, ut0, A2buf);
    k_projscan<<<NB * NK * NLT, 192, 0, stream>>>(x, xT, xpw, dtw, dtb, A2buf,
                                                  Ds, ut0, Cbuf, cumS, ybuf, Hend);
    k_s2<<<NB * NK * NCH, 192, 0, stream>>>(cumS, A2buf, Hend);
    k_fix<<<NB * NK * NLT * 2, 192, 0, stream>>>(Cbuf, cumS, Hend, A2buf, ybuf);
    k_merge<<<NB * NH * 4, 256, 0, stream>>>(ybuf, out);
}